// Round 8
// baseline (3068.850 us; speedup 1.0000x reference)
//
#include <hip/hip_runtime.h>
#include <stdint.h>

// Problem constants (GatedGraphConv_26585847562966)
#define NN  100000   // nodes
#define DD  128      // feature dim
#define TT  3        // timesteps
#define ETT 4        // edge types
#define EE  250000   // edges per type
#define NCH 49       // scan chunks (2048 elems each) over NN
#define GRUGRID 512  // k_gru blocks (2/CU)
#define ECHUNK 1024  // staged edges per LDS chunk

typedef float  f32x4  __attribute__((ext_vector_type(4)));
typedef __bf16 bf16x8 __attribute__((ext_vector_type(8)));

__device__ __forceinline__ float bf2f(uint32_t u){ u <<= 16; return __builtin_bit_cast(float, u); }
__device__ __forceinline__ uint32_t f2bf(float f){
  uint32_t u = __builtin_bit_cast(uint32_t, f);
  return (u + 0x7FFFu + ((u >> 16) & 1u)) >> 16;   // RNE, low 16 bits valid
}
__device__ __forceinline__ f32x4 mfma16(bf16x8 a, bf16x8 b, f32x4 c){
  return __builtin_amdgcn_mfma_f32_16x16x32_bf16(a, b, c, 0, 0, 0);
}

// ---------------------------------------------------------------- merged CSR build
__global__ void k_count_m(const int* __restrict__ erow, const float* __restrict__ eval,
                          int* __restrict__ counts_m, float* __restrict__ degval){
  int idx = blockIdx.x * 256 + threadIdx.x;
  if (idx >= ETT * EE) return;
  int e = idx / EE;
  int row = erow[idx];
  atomicAdd(&counts_m[row], 1);
  atomicAdd(&degval[e * NN + row], eval[idx]);
}

__global__ void k_blksum_m(const int* __restrict__ counts, int* __restrict__ bsum){
  const int b = blockIdx.x;
  const int* p = counts + b * 2048;
  int lim = NN - b * 2048; if (lim > 2048) lim = 2048;
  const int t = threadIdx.x;
  int s = 0;
  #pragma unroll
  for (int i = 0; i < 8; ++i){
    int idx = i * 256 + t;
    if (idx < lim) s += p[idx];
  }
  #pragma unroll
  for (int d = 32; d; d >>= 1) s += __shfl_down(s, d);
  __shared__ int wsum[4];
  if ((t & 63) == 0) wsum[t >> 6] = s;
  __syncthreads();
  if (t == 0) bsum[b] = wsum[0] + wsum[1] + wsum[2] + wsum[3];
}

__global__ void k_scanp_m(const int* __restrict__ bsum, int* __restrict__ bexc,
                          int* __restrict__ offm){
  const int l = threadIdx.x;                      // 64 threads, NCH=49 < 64
  int v = (l < NCH) ? bsum[l] : 0;
  int x = v;
  #pragma unroll
  for (int d = 1; d < 64; d <<= 1){ int y = __shfl_up(x, d); if (l >= d) x += y; }
  if (l < NCH) bexc[l] = x - v;
  if (l == NCH - 1) offm[NN] = x;
}

__global__ void k_apply_m(const int* __restrict__ counts, const int* __restrict__ bexc,
                          int* __restrict__ offm){
  const int b = blockIdx.x;
  const int* p = counts + b * 2048;
  int* off = offm + b * 2048;
  int lim = NN - b * 2048; if (lim > 2048) lim = 2048;
  const int t = threadIdx.x, l = t & 63, wid = t >> 6;
  __shared__ int wt[4];
  int v[8], s = 0;
  #pragma unroll
  for (int i = 0; i < 8; ++i){
    int idx = t * 8 + i;
    v[i] = (idx < lim) ? p[idx] : 0; s += v[i];
  }
  int x = s;
  #pragma unroll
  for (int d = 1; d < 64; d <<= 1){ int y = __shfl_up(x, d); if (l >= d) x += y; }
  if (l == 63) wt[wid] = x;
  __syncthreads();
  int wexc = 0;
  #pragma unroll
  for (int k = 0; k < 4; ++k) if (k < wid) wexc += wt[k];
  int te = bexc[b] + wexc + (x - s);
  #pragma unroll
  for (int i = 0; i < 8; ++i){
    int idx = t * 8 + i;
    if (idx < lim) off[idx] = te;
    te += v[i];
  }
}

// merged fill: payload = (col | etype<<17 | (row&31)<<19, val)  — col < 2^17
__global__ void k_fill_m(const int* __restrict__ erow, const int* __restrict__ ecol,
                         const float* __restrict__ eval, const int* __restrict__ offm,
                         int* __restrict__ cursor, uint2* __restrict__ sedge_m){
  int idx = blockIdx.x * 256 + threadIdx.x;
  if (idx >= ETT * EE) return;
  int e = idx / EE;
  int row = erow[idx];
  int pos = atomicAdd(&cursor[row], 1);
  int o = offm[row] + pos;
  sedge_m[o] = make_uint2((uint32_t)ecol[idx] | ((uint32_t)e << 17) | (((uint32_t)row & 31u) << 19),
                          __builtin_bit_cast(uint32_t, eval[idx]));
}

// ---------------------------------------------------------------- converts
__global__ void k_conv_x(const float* __restrict__ x, uint16_t* __restrict__ hbf){
  int idx = blockIdx.x * 256 + threadIdx.x;       // one uint4 (8 bf16) per thread
  const float4* xp = (const float4*)x;
  float4 a = xp[idx * 2], b = xp[idx * 2 + 1];
  uint32_t p0 = f2bf(a.x) | (f2bf(a.y) << 16);
  uint32_t p1 = f2bf(a.z) | (f2bf(a.w) << 16);
  uint32_t p2 = f2bf(b.x) | (f2bf(b.y) << 16);
  uint32_t p3 = f2bf(b.z) | (f2bf(b.w) << 16);
  ((uint4*)hbf)[idx] = make_uint4(p0, p1, p2, p3);
}

// wcatT[t][f][e*128+d] = weight[t][e][d][f]   (B^T layout: contiguous-k fragments)
__global__ void k_conv_w(const float* __restrict__ weight, const float* __restrict__ wih,
                         const float* __restrict__ whh, const float* __restrict__ bih,
                         const float* __restrict__ bhh, uint16_t* __restrict__ wcatT,
                         uint16_t* __restrict__ wihb, uint16_t* __restrict__ whhb,
                         float* __restrict__ bcomb){
  int idx = blockIdx.x * 256 + threadIdx.x;
  if (idx < TT * 128 * 512){
    int t = idx / 65536; int rem = idx - t * 65536;
    int f = rem >> 9; int u = rem & 511;
    int e = u >> 7; int d = u & 127;
    wcatT[idx] = (uint16_t)f2bf(weight[(((t * 4 + e) * 128 + d) << 7) + f]);
  }
  if (idx < 384 * 128){
    wihb[idx] = (uint16_t)f2bf(wih[idx]);
    whhb[idx] = (uint16_t)f2bf(whh[idx]);
  }
  if (idx < 256) bcomb[idx] = bih[idx] + bhh[idx];
}

// ------------------------------------------------- fused gather + GEMM1
// Edge-balanced gather: block's edges staged to LDS; threads sweep edges
// round-robin (32 slots x 32 dim-lanes, 4 edges in flight, no dependent
// chain, no degree tail); accumulate into LDS f32 agg[lrow][et][j][q] via
// ds_add_f32 (bank-conflict-free: lanes q=0..31 hit distinct banks).
// Then f32 -> swizzled bf16 aggT (LDS reuse) -> M=32 MFMA GEMM vs wcatT.
__global__ __launch_bounds__(1024, 8) void k_agg_gemm(
    const uint16_t* __restrict__ hbf, const int* __restrict__ offm,
    const uint2* __restrict__ sedge_m, const float* __restrict__ degval,
    const float* __restrict__ bias_w, const uint16_t* __restrict__ wcatT_t,
    int tstep, uint16_t* __restrict__ m_out)
{
  __shared__ float agg[32 * 512];                 // 64 KiB f32; first 32 KiB reused as bf16 aggT
  __shared__ uint2 lds_e[ECHUNK];                 // 8 KiB staged edges
  const int tid = threadIdx.x;
  const int node0 = blockIdx.x * 32;              // 3125 blocks exact

  { // zero agg (16 f32/thread)
    f32x4 z = {0.f, 0.f, 0.f, 0.f};
    #pragma unroll
    for (int i = 0; i < 4; ++i) *(f32x4*)&agg[tid * 16 + i * 4] = z;
  }
  const int s  = offm[node0];
  const int en = offm[node0 + 32];
  __syncthreads();

  const int es = tid >> 5, q = tid & 31;          // edge slot, dim quarter-lane
  #pragma unroll 1
  for (int cb = s; cb < en; cb += ECHUNK){        // block-uniform chunk loop
    const int cnt = min(en - cb, ECHUNK);
    if (tid < cnt) lds_e[tid] = sedge_m[cb + tid];
    __syncthreads();

    #pragma unroll 1
    for (int k0 = es; k0 < cnt; k0 += 128){       // 4 edges per iteration
      uint2 ed[4]; uint2 hh[4]; float vv[4];
      #pragma unroll
      for (int i = 0; i < 4; ++i){
        const int k = k0 + 32 * i;
        const int kc = (k < cnt) ? k : (cnt - 1);
        ed[i] = lds_e[kc];
        vv[i] = (k < cnt) ? __builtin_bit_cast(float, ed[i].y) : 0.f;
      }
      #pragma unroll
      for (int i = 0; i < 4; ++i){
        const uint32_t col = ed[i].x & 0x1FFFFu;
        hh[i] = *(const uint2*)(hbf + (size_t)col * DD + q * 4);
      }
      #pragma unroll
      for (int i = 0; i < 4; ++i){
        const uint32_t et   = (ed[i].x >> 17) & 3u;
        const uint32_t lrow = (ed[i].x >> 19) & 31u;
        float* base = &agg[lrow * 512 + et * 128 + q];
        const float v = vv[i];
        atomicAdd(base,      v * bf2f(hh[i].x & 0xffffu));   // j=0: dim q*4+0
        atomicAdd(base + 32, v * bf2f(hh[i].x >> 16));       // j=1
        atomicAdd(base + 64, v * bf2f(hh[i].y & 0xffffu));   // j=2
        atomicAdd(base + 96, v * bf2f(hh[i].y >> 16));       // j=3
      }
    }
    __syncthreads();
  }

  // readback: f32 agg -> swizzled bf16 aggT (reuse agg's first 32 KiB)
  uint16_t* aggT = (uint16_t*)agg;
  {
    const int nl = tid >> 5, cc = tid & 31;       // node, chunk-pair
    uint4 pend[2];
    #pragma unroll
    for (int t2 = 0; t2 < 2; ++t2){
      const int c = cc * 2 + t2;                  // logical 16B chunk 0..63
      const int et = c >> 4, c8 = c & 15;
      const float* b = &agg[nl * 512 + et * 128 + c8 * 2];
      const float2 v0 = *(const float2*)(b);
      const float2 v1 = *(const float2*)(b + 32);
      const float2 v2 = *(const float2*)(b + 64);
      const float2 v3 = *(const float2*)(b + 96);
      pend[t2].x = f2bf(v0.x) | (f2bf(v1.x) << 16);
      pend[t2].y = f2bf(v2.x) | (f2bf(v3.x) << 16);
      pend[t2].z = f2bf(v0.y) | (f2bf(v1.y) << 16);
      pend[t2].w = f2bf(v2.y) | (f2bf(v3.y) << 16);
    }
    __syncthreads();                              // all f32 reads done before bf16 overwrite
    #pragma unroll
    for (int t2 = 0; t2 < 2; ++t2){
      const int c = cc * 2 + t2;
      const int cs = c ^ (nl & 7);
      *(uint4*)&aggT[nl * 512 + cs * 8] = pend[t2];
    }
  }
  __syncthreads();

  // GEMM: C[32x128] = aggT[32x512] * Wcat[512x128]
  // 16 waves: rt = w&1 (16-row tile), fc = w>>1 (16-col tile); 16 MFMA/wave
  const int lane = tid & 63, w = tid >> 6;
  const int rlo = lane & 15, kg = lane >> 4;
  const int rt = w & 1, fc = w >> 1;
  const int rowA = rt * 16 + rlo;
  f32x4 C = f32x4{0.f, 0.f, 0.f, 0.f};

  #pragma unroll
  for (int ks = 0; ks < 16; ++ks){
    const int cs = (ks * 4 + kg) ^ (rowA & 7);
    bf16x8 a = __builtin_bit_cast(bf16x8, *(const uint4*)&aggT[rowA * 512 + cs * 8]);
    bf16x8 b = __builtin_bit_cast(bf16x8,
        *(const uint4*)(wcatT_t + (size_t)(fc * 16 + rlo) * 512 + ks * 32 + kg * 8));
    C = mfma16(a, b, C);
  }

  const float* bwt = bias_w + tstep * (ETT * DD);
  const int f = fc * 16 + rlo;
  const float b0 = bwt[f], b1 = bwt[128 + f], b2 = bwt[256 + f], b3 = bwt[384 + f];
  #pragma unroll
  for (int r = 0; r < 4; ++r){
    const int n2 = node0 + rt * 16 + kg * 4 + r;
    const float bias = degval[n2] * b0 + degval[NN + n2] * b1
                     + degval[2 * NN + n2] * b2 + degval[3 * NN + n2] * b3;
    m_out[(size_t)n2 * DD + f] = (uint16_t)f2bf(C[r] + bias);
  }
}

// ------------------------------------------------- GRU: weights in VGPRs
// Block = 512 thr (8 waves). Wave w owns dims [w*16, w*16+16) for all 3 gates,
// BOTH matrices: 24 bf16x8 A-fragments = 96 VGPRs, loaded ONCE from global.
// Block grid-strides over 32-node tiles; per tile, m_sum/h rows are staged into
// a double-buffered 2x(8KB+8KB) XOR-swizzled LDS tile. Lane (rlo,kg) holds all
// six gate pre-activations for node (tile*32+ns*16+rlo), d = w*16+kg*4+r.
// hbf ping-pongs across dispatches.
__global__ __launch_bounds__(512, 2) void k_gru(
    const uint16_t* __restrict__ m_sum, const uint16_t* __restrict__ hsrc,
    uint16_t* __restrict__ hdst, const float* __restrict__ h_old,
    float* __restrict__ h_new, const uint16_t* __restrict__ wihb,
    const uint16_t* __restrict__ whhb, const float* __restrict__ bcomb,
    const float* __restrict__ b_ih, const float* __restrict__ b_hh)
{
  __shared__ uint4 mt[2][512];                    // [buf][node*16 + chunk] 8KB each
  __shared__ uint4 ht[2][512];
  const int tid = threadIdx.x;
  const int lane = tid & 63, w = tid >> 6;
  const int rlo = lane & 15, kg = lane >> 4;

  // --- preload weight fragments (persistent in VGPRs) ---
  bf16x8 wa[3][4], wb[3][4];                      // [gate][ks]
  #pragma unroll
  for (int g = 0; g < 3; ++g){
    const int j = g * 128 + w * 16 + rlo;
    #pragma unroll
    for (int ks = 0; ks < 4; ++ks){
      wa[g][ks] = __builtin_bit_cast(bf16x8, *(const uint4*)(wihb + j * 128 + ks * 32 + kg * 8));
      wb[g][ks] = __builtin_bit_cast(bf16x8, *(const uint4*)(whhb + j * 128 + ks * 32 + kg * 8));
    }
  }
  // --- per-lane output dims + biases (constant over tiles) ---
  const int d0 = w * 16 + kg * 4;
  const f32x4 brz = *(const f32x4*)(bcomb + d0);
  const f32x4 bzz = *(const f32x4*)(bcomb + 128 + d0);
  const f32x4 bin = *(const f32x4*)(b_ih + 256 + d0);
  const f32x4 bhn = *(const f32x4*)(b_hh + 256 + d0);

  // --- staging map: thread -> (node sn, LDS slot scs), source chunk sc ---
  const int sn  = tid >> 4;                       // 0..31
  const int scs = tid & 15;                       // swizzled slot
  const int sc  = scs ^ (sn & 7);                 // logical chunk (involution)

  const int NT = NN / 32;                         // 3125
  int tile = blockIdx.x;
  { // prologue: stage tile 0 into buf 0
    const size_t base = ((size_t)(tile * 32 + sn)) * DD + sc * 8;
    mt[0][sn * 16 + scs] = *(const uint4*)(m_sum + base);
    ht[0][sn * 16 + scs] = *(const uint4*)(hsrc + base);
  }
  __syncthreads();

  int buf = 0;
  #pragma unroll 1
  for (; tile < NT; tile += GRUGRID){
    // issue next tile's stage loads (consumed after the barrier below)
    const int ntile = tile + GRUGRID;
    const bool have = ntile < NT;                 // block-uniform
    uint4 mv, hv;
    if (have){
      const size_t nbase = ((size_t)(ntile * 32 + sn)) * DD + sc * 8;
      mv = *(const uint4*)(m_sum + nbase);
      hv = *(const uint4*)(hsrc + nbase);
    }

    // --- MFMA phase: 48 MFMAs per wave from LDS B-fragments ---
    f32x4 acc[3][2][2];                           // [gate][mat][nsub]
    #pragma unroll
    for (int g = 0; g < 3; ++g)
      #pragma unroll
      for (int m = 0; m < 2; ++m)
        #pragma unroll
        for (int ns = 0; ns < 2; ++ns) acc[g][m][ns] = f32x4{0.f,0.f,0.f,0.f};

    #pragma unroll
    for (int ks = 0; ks < 4; ++ks){
      #pragma unroll
      for (int ns = 0; ns < 2; ++ns){
        const int node = ns * 16 + rlo;
        const int cs = (ks * 4 + kg) ^ (node & 7);
        const bf16x8 bm = __builtin_bit_cast(bf16x8, mt[buf][node * 16 + cs]);
        const bf16x8 bh = __builtin_bit_cast(bf16x8, ht[buf][node * 16 + cs]);
        #pragma unroll
        for (int g = 0; g < 3; ++g){
          acc[g][0][ns] = mfma16(wa[g][ks], bm, acc[g][0][ns]);
          acc[g][1][ns] = mfma16(wb[g][ks], bh, acc[g][1][ns]);
        }
      }
    }

    // --- GRU epilogue, fully in-lane ---
    #pragma unroll
    for (int ns = 0; ns < 2; ++ns){
      const int node = tile * 32 + ns * 16 + rlo;
      const f32x4 ho = *(const f32x4*)(h_old + (size_t)node * DD + d0);
      float hvv[4];
      #pragma unroll
      for (int r = 0; r < 4; ++r){
        const float rg = 1.f / (1.f + __expf(-(acc[0][0][ns][r] + acc[0][1][ns][r] + brz[r])));
        const float zg = 1.f / (1.f + __expf(-(acc[1][0][ns][r] + acc[1][1][ns][r] + bzz[r])));
        const float xa = (acc[2][0][ns][r] + bin[r]) + rg * (acc[2][1][ns][r] + bhn[r]);
        const float ng = 1.f - 2.f / (__expf(2.f * xa) + 1.f);   // tanh
        hvv[r] = (1.f - zg) * ng + zg * ho[r];
      }
      *(f32x4*)(h_new + (size_t)node * DD + d0) = f32x4{hvv[0], hvv[1], hvv[2], hvv[3]};
      uint32_t p0 = f2bf(hvv[0]) | (f2bf(hvv[1]) << 16);
      uint32_t p1 = f2bf(hvv[2]) | (f2bf(hvv[3]) << 16);
      *(uint2*)(hdst + (size_t)node * DD + d0) = make_uint2(p0, p1);
    }

    // --- write next tile into the other buffer; one barrier per tile ---
    if (have){
      mt[buf ^ 1][sn * 16 + scs] = mv;
      ht[buf ^ 1][sn * 16 + scs] = hv;
    }
    __syncthreads();
    buf ^= 1;
  }
}

// ---------------------------------------------------------------- launch
extern "C" void kernel_launch(void* const* d_in, const int* in_sizes, int n_in,
                              void* d_out, int out_size, void* d_ws, size_t ws_size,
                              hipStream_t stream) {
  const float* x      = (const float*)d_in[0];
  const int*   erow   = (const int*)d_in[1];
  const int*   ecol   = (const int*)d_in[2];
  const float* eval   = (const float*)d_in[3];
  const float* weight = (const float*)d_in[4];
  const float* bias_w = (const float*)d_in[5];
  const float* wih    = (const float*)d_in[6];
  const float* whh    = (const float*)d_in[7];
  const float* bih    = (const float*)d_in[8];
  const float* bhh    = (const float*)d_in[9];
  float* out = (float*)d_out;
  char* ws = (char*)d_ws;

  size_t o = 0;
  auto alloc = [&](size_t bytes)->char*{ char* p = ws + o; o += (bytes + 255) & ~(size_t)255; return p; };
  int*      counts_m = (int*)     alloc((size_t)NN * 4);             // zeroed
  int*      cursor_m = (int*)     alloc((size_t)NN * 4);             // zeroed
  float*    degval   = (float*)   alloc((size_t)ETT * NN * 4);       // zeroed
  int*      offm     = (int*)     alloc((size_t)(NN + 1) * 4);
  int*      bsum     = (int*)     alloc((size_t)NCH * 4);
  int*      bexc     = (int*)     alloc((size_t)NCH * 4);
  uint2*    sedge_m  = (uint2*)   alloc((size_t)ETT * EE * 8);
  float*    hf       = (float*)   alloc((size_t)NN * DD * 4);
  uint16_t* hbf0     = (uint16_t*)alloc((size_t)NN * DD * 2);
  uint16_t* hbf1     = (uint16_t*)alloc((size_t)NN * DD * 2);
  uint16_t* msum     = (uint16_t*)alloc((size_t)NN * DD * 2);
  uint16_t* wcatT    = (uint16_t*)alloc((size_t)TT * 128 * 512 * 2);
  uint16_t* wihb     = (uint16_t*)alloc((size_t)384 * 128 * 2);
  uint16_t* whhb     = (uint16_t*)alloc((size_t)384 * 128 * 2);
  float*    bcomb    = (float*)   alloc((size_t)256 * 4);
  (void)ws_size; (void)in_sizes; (void)n_in; (void)out_size;

  // zero counts_m + cursor_m + degval (contiguous span incl. alignment padding)
  const size_t zspan = (size_t)((char*)degval - (char*)counts_m) + (size_t)ETT * NN * 4;
  hipMemsetAsync(counts_m, 0, zspan, stream);

  k_count_m<<<(ETT * EE + 255) / 256, 256, 0, stream>>>(erow, eval, counts_m, degval);
  k_blksum_m<<<NCH, 256, 0, stream>>>(counts_m, bsum);
  k_scanp_m<<<1, 64, 0, stream>>>(bsum, bexc, offm);
  k_apply_m<<<NCH, 256, 0, stream>>>(counts_m, bexc, offm);
  k_fill_m<<<(ETT * EE + 255) / 256, 256, 0, stream>>>(erow, ecol, eval, offm, cursor_m, sedge_m);
  k_conv_x<<<(NN * DD / 8) / 256, 256, 0, stream>>>(x, hbf0);
  k_conv_w<<<(TT * 128 * 512 + 255) / 256, 256, 0, stream>>>(weight, wih, whh, bih, bhh,
                                                             wcatT, wihb, whhb, bcomb);

  uint16_t* hsrc = hbf0;
  uint16_t* hdst = hbf1;
  for (int t = 0; t < TT; ++t){
    k_agg_gemm<<<NN / 32, 1024, 0, stream>>>(hsrc, offm, sedge_m, degval,
                                             bias_w, wcatT + (size_t)t * 65536, t, msum);
    const float* hold = (t == 0) ? x : hf;
    float* hnew = (t == TT - 1) ? out : hf;
    k_gru<<<GRUGRID, 512, 0, stream>>>(msum, hsrc, hdst, hold, hnew,
                                       wihb, whhb, bcomb, bih, bhh);
    uint16_t* tmp = hsrc; hsrc = hdst; hdst = tmp;
  }
}

// Round 9
// 721.032 us; speedup vs baseline: 4.2562x; 4.2562x over previous
//
#include <hip/hip_runtime.h>
#include <stdint.h>

// Problem constants (GatedGraphConv_26585847562966)
#define NN  100000   // nodes
#define DD  128      // feature dim
#define TT  3        // timesteps
#define ETT 4        // edge types
#define EE  250000   // edges per type
#define NCH 49       // scan chunks per edge type (2048 elems each)

typedef float  f32x4  __attribute__((ext_vector_type(4)));
typedef __bf16 bf16x8 __attribute__((ext_vector_type(8)));

__device__ __forceinline__ float bf2f(uint32_t u){ u <<= 16; return __builtin_bit_cast(float, u); }
__device__ __forceinline__ uint32_t f2bf(float f){
  uint32_t u = __builtin_bit_cast(uint32_t, f);
  return (u + 0x7FFFu + ((u >> 16) & 1u)) >> 16;   // RNE, low 16 bits valid
}
__device__ __forceinline__ f32x4 mfma16(bf16x8 a, bf16x8 b, f32x4 c){
  return __builtin_amdgcn_mfma_f32_16x16x32_bf16(a, b, c, 0, 0, 0);
}

// ---------------------------------------------------------------- CSR build (per etype)
__global__ void k_count(const int* __restrict__ erow, const float* __restrict__ eval,
                        int* __restrict__ counts, float* __restrict__ degval){
  int idx = blockIdx.x * 256 + threadIdx.x;
  if (idx >= ETT * EE) return;
  int e = idx / EE;
  int row = erow[idx];
  atomicAdd(&counts[e * NN + row], 1);
  atomicAdd(&degval[e * NN + row], eval[idx]);
}

__global__ void k_blksum(const int* __restrict__ counts, int* __restrict__ bsum){
  const int b = blockIdx.x, e = b / NCH, c = b % NCH;
  const int* p = counts + e * NN + c * 2048;
  int lim = NN - c * 2048; if (lim > 2048) lim = 2048;
  const int t = threadIdx.x;
  int s = 0;
  #pragma unroll
  for (int i = 0; i < 8; ++i){
    int idx = i * 256 + t;
    if (idx < lim) s += p[idx];
  }
  #pragma unroll
  for (int d = 32; d; d >>= 1) s += __shfl_down(s, d);
  __shared__ int wsum[4];
  if ((t & 63) == 0) wsum[t >> 6] = s;
  __syncthreads();
  if (t == 0) bsum[b] = wsum[0] + wsum[1] + wsum[2] + wsum[3];
}

__global__ void k_scanp(const int* __restrict__ bsum, int* __restrict__ bexc,
                        int* __restrict__ offsets){
  const int t = threadIdx.x, wid = t >> 6, l = t & 63;
  int v = (l < NCH) ? bsum[wid * NCH + l] : 0;
  int x = v;
  #pragma unroll
  for (int d = 1; d < 64; d <<= 1){ int y = __shfl_up(x, d); if (l >= d) x += y; }
  if (l < NCH) bexc[wid * NCH + l] = x - v;
  if (l == NCH - 1) offsets[wid * (NN + 1) + NN] = x;
}

__global__ void k_apply(const int* __restrict__ counts, const int* __restrict__ bexc,
                        int* __restrict__ offsets){
  const int b = blockIdx.x, e = b / NCH, c = b % NCH;
  const int* p = counts + e * NN + c * 2048;
  int* off = offsets + e * (NN + 1) + c * 2048;
  int lim = NN - c * 2048; if (lim > 2048) lim = 2048;
  const int t = threadIdx.x, l = t & 63, wid = t >> 6;
  __shared__ int wt[4];
  int v[8], s = 0;
  #pragma unroll
  for (int i = 0; i < 8; ++i){
    int idx = t * 8 + i;
    v[i] = (idx < lim) ? p[idx] : 0; s += v[i];
  }
  int x = s;
  #pragma unroll
  for (int d = 1; d < 64; d <<= 1){ int y = __shfl_up(x, d); if (l >= d) x += y; }
  if (l == 63) wt[wid] = x;
  __syncthreads();
  int wexc = 0;
  #pragma unroll
  for (int k = 0; k < 4; ++k) if (k < wid) wexc += wt[k];
  int te = bexc[b] + wexc + (x - s);
  #pragma unroll
  for (int i = 0; i < 8; ++i){
    int idx = t * 8 + i;
    if (idx < lim) off[idx] = te;
    te += v[i];
  }
}

__global__ void k_fill(const int* __restrict__ erow, const int* __restrict__ ecol,
                       const float* __restrict__ eval, const int* __restrict__ offsets,
                       int* __restrict__ cursor, uint2* __restrict__ sedge){
  int idx = blockIdx.x * 256 + threadIdx.x;
  if (idx >= ETT * EE) return;
  int e = idx / EE;
  int row = erow[idx];
  int pos = atomicAdd(&cursor[e * NN + row], 1);
  int o = offsets[e * (NN + 1) + row] + pos;
  sedge[e * EE + o] = make_uint2((uint32_t)ecol[idx], __builtin_bit_cast(uint32_t, eval[idx]));
}

// ---------------------------------------------------------------- converts
__global__ void k_conv_x(const float* __restrict__ x, uint16_t* __restrict__ hbf){
  int idx = blockIdx.x * 256 + threadIdx.x;       // one uint4 (8 bf16) per thread
  const float4* xp = (const float4*)x;
  float4 a = xp[idx * 2], b = xp[idx * 2 + 1];
  uint32_t p0 = f2bf(a.x) | (f2bf(a.y) << 16);
  uint32_t p1 = f2bf(a.z) | (f2bf(a.w) << 16);
  uint32_t p2 = f2bf(b.x) | (f2bf(b.y) << 16);
  uint32_t p3 = f2bf(b.z) | (f2bf(b.w) << 16);
  ((uint4*)hbf)[idx] = make_uint4(p0, p1, p2, p3);
}

// wcatT[t][f][e*128+d] = weight[t][e][d][f]   (B^T layout, GEMM1 B-fragments)
// wgru: fragment-major GRU A-operands: frag = (((w*3+g)*2+m)*2+bb)*4+ks,
//       elem [frag][lane][i] = Wm[g*128 + w*32 + bb*16 + (lane&15)][ks*32+(lane>>4)*8+i]
__global__ void k_conv_w(const float* __restrict__ weight, const float* __restrict__ wih,
                         const float* __restrict__ whh, const float* __restrict__ bih,
                         const float* __restrict__ bhh, uint16_t* __restrict__ wcatT,
                         uint16_t* __restrict__ wgru, float* __restrict__ bcomb){
  int idx = blockIdx.x * 256 + threadIdx.x;
  if (idx < TT * 128 * 512){
    int t = idx / 65536; int rem = idx - t * 65536;
    int f = rem >> 9; int u = rem & 511;
    int e = u >> 7; int d = u & 127;
    wcatT[idx] = (uint16_t)f2bf(weight[(((t * 4 + e) * 128 + d) << 7) + f]);
  }
  if (idx < 192 * 512){                           // 98304 wgru elems
    const int frag = idx >> 9, within = idx & 511;
    const int lane = within >> 3, i = within & 7;
    const int ks = frag & 3, bb = (frag >> 2) & 1, m = (frag >> 3) & 1;
    const int rem2 = frag >> 4;                   // 0..11
    const int g = rem2 % 3, w = rem2 / 3;
    const int j = g * 128 + w * 32 + bb * 16 + (lane & 15);
    const int k = ks * 32 + (lane >> 4) * 8 + i;
    const float* src = m ? whh : wih;
    wgru[idx] = (uint16_t)f2bf(src[j * 128 + k]);
  }
  if (idx < 256) bcomb[idx] = bih[idx] + bhh[idx];
}

// ------------------------------------------------- fused gather + GEMM1 + GRU
// Phase 1 (R5 champion): per-etype CSR gather, 4-way edge batching, 32-node
//   swizzled bf16 aggT (32 KiB).
// Phase 2: C[32x128] = aggT * Wcat (4 waves, 64 MFMA/wave) + deg-weighted bias.
// Phase 3: m_sum -> LDS mT (reuses aggT front 8KB); h rows staged to hT.
// Phase 4: GRU via MFMA: A = wgru fragments (global, L1/L2-hot, coalesced),
//   B = mT/hT; two bb-passes keep acc at 48 VGPR; in-lane gate epilogue
//   writes h_new (f32) and hdst (bf16 ping-pong).
#define ACC8(val, u, base) \
  acc[base+0] += val * bf2f(u.x & 0xffffu); acc[base+1] += val * bf2f(u.x >> 16); \
  acc[base+2] += val * bf2f(u.y & 0xffffu); acc[base+3] += val * bf2f(u.y >> 16); \
  acc[base+4] += val * bf2f(u.z & 0xffffu); acc[base+5] += val * bf2f(u.z >> 16); \
  acc[base+6] += val * bf2f(u.w & 0xffffu); acc[base+7] += val * bf2f(u.w >> 16);

__global__ __launch_bounds__(256, 4) void k_step(
    const uint16_t* __restrict__ hsrc, uint16_t* __restrict__ hdst,
    const float* __restrict__ h_old, float* __restrict__ h_new,
    const int* __restrict__ offsets, const uint2* __restrict__ sedge,
    const float* __restrict__ degval, const float* __restrict__ bias_w,
    const uint16_t* __restrict__ wcatT_t, int tstep,
    const uint16_t* __restrict__ wgru, const float* __restrict__ bcomb,
    const float* __restrict__ b_ih, const float* __restrict__ b_hh)
{
  __shared__ uint16_t aggT[32 * 512];             // 32 KiB; front 8 KiB reused as mT
  __shared__ uint4 hT4[512];                      // 8 KiB staged h rows (swizzled)
  const int tid = threadIdx.x;
  const int node0 = blockIdx.x * 32;              // 3125 blocks exact

  { // ---- Phase 1: gather (R5 champion, verbatim) ----
    const int nl = tid >> 3, q = tid & 7;
    const int n = node0 + nl;
    int se[4], ne[4];
    #pragma unroll
    for (int e = 0; e < ETT; ++e){
      se[e] = offsets[e * (NN + 1) + n];
      ne[e] = offsets[e * (NN + 1) + n + 1];
    }
    #pragma unroll 1
    for (int e = 0; e < ETT; ++e){
      float acc[16];
      #pragma unroll
      for (int i = 0; i < 16; ++i) acc[i] = 0.f;
      const int s = se[e], en = ne[e];
      const uint2* ep = sedge + (size_t)e * EE;
      #pragma unroll 1
      for (int i = s; i < en; i += 4){
        const int last = en - 1;
        const int i1 = (i + 1 < last) ? i + 1 : last;
        const int i2 = (i + 2 < last) ? i + 2 : last;
        const int i3 = (i + 3 < last) ? i + 3 : last;
        const uint2 cv0 = ep[i], cv1 = ep[i1], cv2 = ep[i2], cv3 = ep[i3];
        const float v0 = __builtin_bit_cast(float, cv0.y);
        const float v1 = (i + 1 <= last) ? __builtin_bit_cast(float, cv1.y) : 0.f;
        const float v2 = (i + 2 <= last) ? __builtin_bit_cast(float, cv2.y) : 0.f;
        const float v3 = (i + 3 <= last) ? __builtin_bit_cast(float, cv3.y) : 0.f;
        const uint4* p0 = (const uint4*)(hsrc + (size_t)cv0.x * DD + q * 16);
        const uint4* p1 = (const uint4*)(hsrc + (size_t)cv1.x * DD + q * 16);
        const uint4* p2 = (const uint4*)(hsrc + (size_t)cv2.x * DD + q * 16);
        const uint4* p3 = (const uint4*)(hsrc + (size_t)cv3.x * DD + q * 16);
        const uint4 a0 = p0[0], b0 = p0[1];
        const uint4 a1 = p1[0], b1 = p1[1];
        const uint4 a2 = p2[0], b2 = p2[1];
        const uint4 a3 = p3[0], b3 = p3[1];
        ACC8(v0, a0, 0); ACC8(v0, b0, 8);
        ACC8(v1, a1, 0); ACC8(v1, b1, 8);
        ACC8(v2, a2, 0); ACC8(v2, b2, 8);
        ACC8(v3, a3, 0); ACC8(v3, b3, 8);
      }
      #pragma unroll
      for (int c2 = 0; c2 < 2; ++c2){
        const int c  = e * 16 + q * 2 + c2;       // logical 16B chunk (0..63)
        const int cs = c ^ (nl & 7);
        uint32_t p0 = f2bf(acc[c2*8+0]) | (f2bf(acc[c2*8+1]) << 16);
        uint32_t p1 = f2bf(acc[c2*8+2]) | (f2bf(acc[c2*8+3]) << 16);
        uint32_t p2 = f2bf(acc[c2*8+4]) | (f2bf(acc[c2*8+5]) << 16);
        uint32_t p3 = f2bf(acc[c2*8+6]) | (f2bf(acc[c2*8+7]) << 16);
        *(uint4*)&aggT[nl * 512 + cs * 8] = make_uint4(p0, p1, p2, p3);
      }
    }
  }
  __syncthreads();

  const int lane = tid & 63, w = tid >> 6;
  const int rlo = lane & 15, kg = lane >> 4;

  // ---- stage hT (independent of aggT; overlaps GEMM) ----
  #pragma unroll
  for (int i = 0; i < 2; ++i){
    const int slot = tid * 2 + i;                 // sn*16 + scs
    const int sn = slot >> 4, scs = slot & 15;
    const int sc = scs ^ (sn & 7);
    hT4[slot] = *(const uint4*)(hsrc + (size_t)(node0 + sn) * DD + sc * 8);
  }

  // ---- Phase 2: GEMM C[32x128] = aggT[32x512] * Wcat[512x128] ----
  const int rt = w & 1, fh = w >> 1;
  const int rowA = rt * 16 + rlo;
  f32x4 C[4];
  #pragma unroll
  for (int i = 0; i < 4; ++i) C[i] = f32x4{0.f, 0.f, 0.f, 0.f};

  #pragma unroll
  for (int ks = 0; ks < 16; ++ks){
    const int cs = (ks * 4 + kg) ^ (rowA & 7);
    bf16x8 a = __builtin_bit_cast(bf16x8, *(const uint4*)&aggT[rowA * 512 + cs * 8]);
    #pragma unroll
    for (int ft = 0; ft < 4; ++ft){
      const int f = fh * 64 + ft * 16 + rlo;
      bf16x8 b = __builtin_bit_cast(bf16x8, *(const uint4*)(wcatT_t + (size_t)f * 512 + ks * 32 + kg * 8));
      C[ft] = mfma16(a, b, C[ft]);
    }
  }

  const float* bwt = bias_w + tstep * (ETT * DD);
  float dv[4][4];
  #pragma unroll
  for (int r = 0; r < 4; ++r){
    const int n2 = node0 + rt * 16 + kg * 4 + r;
    #pragma unroll
    for (int e = 0; e < 4; ++e) dv[e][r] = degval[e * NN + n2];
  }
  __syncthreads();                                // all aggT reads done before mT overwrite

  // ---- Phase 3: m_sum -> mT (swizzled u16 scatter into aggT front 8KB) ----
  uint16_t* mT = aggT;
  #pragma unroll
  for (int ft = 0; ft < 4; ++ft){
    const int f = fh * 64 + ft * 16 + rlo;
    const float b0 = bwt[f], b1 = bwt[128 + f], b2 = bwt[256 + f], b3 = bwt[384 + f];
    #pragma unroll
    for (int r = 0; r < 4; ++r){
      const int n2l = rt * 16 + kg * 4 + r;
      const float bias = dv[0][r]*b0 + dv[1][r]*b1 + dv[2][r]*b2 + dv[3][r]*b3;
      mT[n2l * 128 + (((f >> 3) ^ (n2l & 7)) << 3) + (f & 7)] = (uint16_t)f2bf(C[ft][r] + bias);
    }
  }
  __syncthreads();

  // ---- Phase 4: GRU (wave w owns dims [w*32, w*32+32), two bb-passes) ----
  const uint4* mT4 = (const uint4*)aggT;
  #pragma unroll
  for (int bb = 0; bb < 2; ++bb){
    f32x4 acc[3][2][2];                           // [gate][mat][ns]
    #pragma unroll
    for (int g = 0; g < 3; ++g)
      #pragma unroll
      for (int m = 0; m < 2; ++m)
        #pragma unroll
        for (int ns = 0; ns < 2; ++ns) acc[g][m][ns] = f32x4{0.f,0.f,0.f,0.f};

    #pragma unroll
    for (int ks = 0; ks < 4; ++ks){
      bf16x8 fa[3], fb[3];
      #pragma unroll
      for (int g = 0; g < 3; ++g){
        const int fragA = (((w * 3 + g) * 2 + 0) * 2 + bb) * 4 + ks;
        const int fragB = (((w * 3 + g) * 2 + 1) * 2 + bb) * 4 + ks;
        fa[g] = __builtin_bit_cast(bf16x8, *(const uint4*)(wgru + fragA * 512 + lane * 8));
        fb[g] = __builtin_bit_cast(bf16x8, *(const uint4*)(wgru + fragB * 512 + lane * 8));
      }
      #pragma unroll
      for (int ns = 0; ns < 2; ++ns){
        const int node = ns * 16 + rlo;
        const int cs = (ks * 4 + kg) ^ (node & 7);
        const bf16x8 bm = __builtin_bit_cast(bf16x8, mT4[node * 16 + cs]);
        const bf16x8 bh = __builtin_bit_cast(bf16x8, hT4[node * 16 + cs]);
        #pragma unroll
        for (int g = 0; g < 3; ++g){
          acc[g][0][ns] = mfma16(fa[g], bm, acc[g][0][ns]);
          acc[g][1][ns] = mfma16(fb[g], bh, acc[g][1][ns]);
        }
      }
    }

    const int d0 = w * 32 + bb * 16 + kg * 4;
    const f32x4 brz = *(const f32x4*)(bcomb + d0);
    const f32x4 bzz = *(const f32x4*)(bcomb + 128 + d0);
    const f32x4 bin = *(const f32x4*)(b_ih + 256 + d0);
    const f32x4 bhn = *(const f32x4*)(b_hh + 256 + d0);
    #pragma unroll
    for (int ns = 0; ns < 2; ++ns){
      const int node = node0 + ns * 16 + rlo;
      const f32x4 ho = *(const f32x4*)(h_old + (size_t)node * DD + d0);
      float hv[4];
      #pragma unroll
      for (int r = 0; r < 4; ++r){
        const float rg = 1.f / (1.f + __expf(-(acc[0][0][ns][r] + acc[0][1][ns][r] + brz[r])));
        const float zg = 1.f / (1.f + __expf(-(acc[1][0][ns][r] + acc[1][1][ns][r] + bzz[r])));
        const float xa = (acc[2][0][ns][r] + bin[r]) + rg * (acc[2][1][ns][r] + bhn[r]);
        const float ng = 1.f - 2.f / (__expf(2.f * xa) + 1.f);   // tanh
        hv[r] = (1.f - zg) * ng + zg * ho[r];
      }
      *(f32x4*)(h_new + (size_t)node * DD + d0) = f32x4{hv[0], hv[1], hv[2], hv[3]};
      uint32_t p0 = f2bf(hv[0]) | (f2bf(hv[1]) << 16);
      uint32_t p1 = f2bf(hv[2]) | (f2bf(hv[3]) << 16);
      *(uint2*)(hdst + (size_t)node * DD + d0) = make_uint2(p0, p1);
    }
  }
}

// ---------------------------------------------------------------- launch
extern "C" void kernel_launch(void* const* d_in, const int* in_sizes, int n_in,
                              void* d_out, int out_size, void* d_ws, size_t ws_size,
                              hipStream_t stream) {
  const float* x      = (const float*)d_in[0];
  const int*   erow   = (const int*)d_in[1];
  const int*   ecol   = (const int*)d_in[2];
  const float* eval   = (const float*)d_in[3];
  const float* weight = (const float*)d_in[4];
  const float* bias_w = (const float*)d_in[5];
  const float* wih    = (const float*)d_in[6];
  const float* whh    = (const float*)d_in[7];
  const float* bih    = (const float*)d_in[8];
  const float* bhh    = (const float*)d_in[9];
  float* out = (float*)d_out;
  char* ws = (char*)d_ws;

  size_t o = 0;
  auto alloc = [&](size_t bytes)->char*{ char* p = ws + o; o += (bytes + 255) & ~(size_t)255; return p; };
  int*      counts  = (int*)     alloc((size_t)ETT * NN * 4);        // zeroed
  int*      cursor  = (int*)     alloc((size_t)ETT * NN * 4);        // zeroed
  float*    degval  = (float*)   alloc((size_t)ETT * NN * 4);        // zeroed
  int*      offsets = (int*)     alloc((size_t)ETT * (NN + 1) * 4);
  int*      bsum    = (int*)     alloc((size_t)ETT * NCH * 4);
  int*      bexc    = (int*)     alloc((size_t)ETT * NCH * 4);
  uint2*    sedge   = (uint2*)   alloc((size_t)ETT * EE * 8);
  float*    hf      = (float*)   alloc((size_t)NN * DD * 4);
  uint16_t* hbf0    = (uint16_t*)alloc((size_t)NN * DD * 2);
  uint16_t* hbf1    = (uint16_t*)alloc((size_t)NN * DD * 2);
  uint16_t* wcatT   = (uint16_t*)alloc((size_t)TT * 128 * 512 * 2);
  uint16_t* wgru    = (uint16_t*)alloc((size_t)192 * 512 * 2);
  float*    bcomb   = (float*)   alloc((size_t)256 * 4);
  (void)ws_size; (void)in_sizes; (void)n_in; (void)out_size;

  // counts/cursor/degval contiguous (each 1.6MB, 256-aligned exactly)
  hipMemsetAsync(counts, 0, (size_t)3 * ETT * NN * 4, stream);

  k_count<<<(ETT * EE + 255) / 256, 256, 0, stream>>>(erow, eval, counts, degval);
  k_blksum<<<ETT * NCH, 256, 0, stream>>>(counts, bsum);
  k_scanp<<<1, 256, 0, stream>>>(bsum, bexc, offsets);
  k_apply<<<ETT * NCH, 256, 0, stream>>>(counts, bexc, offsets);
  k_fill<<<(ETT * EE + 255) / 256, 256, 0, stream>>>(erow, ecol, eval, offsets, cursor, sedge);
  k_conv_x<<<(NN * DD / 8) / 256, 256, 0, stream>>>(x, hbf0);
  k_conv_w<<<(TT * 128 * 512 + 255) / 256, 256, 0, stream>>>(weight, wih, whh, bih, bhh,
                                                             wcatT, wgru, bcomb);

  uint16_t* hs = hbf0;
  uint16_t* hd = hbf1;
  for (int t = 0; t < TT; ++t){
    const float* hold = (t == 0) ? x : hf;
    float* hnew = (t == TT - 1) ? out : hf;
    k_step<<<NN / 32, 256, 0, stream>>>(hs, hd, hold, hnew, offsets, sedge, degval,
                                        bias_w, wcatT + (size_t)t * 65536, t,
                                        wgru, bcomb, bih, bhh);
    uint16_t* tmp = hs; hs = hd; hd = tmp;
  }
}